// Round 5
// baseline (862.636 us; speedup 1.0000x reference)
//
#include <hip/hip_runtime.h>
#include <hip/hip_bf16.h>
#include <stdint.h>

// Problem constants
#define S_LEN 4096
#define B_DIM 8
#define E_DIM 1024
#define H_DIM 16
#define M_ROWS (S_LEN * B_DIM)   // 32768
#define N_QKV (3 * E_DIM)        // 3072
#define HB_DIM (H_DIM * B_DIM)   // 128

typedef float f32x4 __attribute__((ext_vector_type(4)));
typedef short bf16x8 __attribute__((ext_vector_type(8)));

#define MFMA16(a, b, c) __builtin_amdgcn_mfma_f32_16x16x32_bf16(a, b, c, 0, 0, 0)

__device__ __forceinline__ short f2bf(float f) {
  __hip_bfloat16 h = __float2bfloat16(f);
  short s;
  __builtin_memcpy(&s, &h, 2);
  return s;
}
__device__ __forceinline__ float bf2f(short b) {
  unsigned u = ((unsigned)(unsigned short)b) << 16;
  float f;
  __builtin_memcpy(&f, &u, 4);
  return f;
}
__device__ __forceinline__ void gl_lds16(const void* g, void* l) {
  __builtin_amdgcn_global_load_lds(
      (const __attribute__((address_space(1))) void*)g,
      (__attribute__((address_space(3))) void*)l, 16, 0, 0);
}

// ---------------------------------------------------------------------------
// K1: cast fp32 -> bf16 for x, w_qkv, w_out, w_f (one thread = 4 elements)
// ---------------------------------------------------------------------------
__global__ __launch_bounds__(256) void cast_all(
    const float* __restrict__ x, const float* __restrict__ wqkv,
    const float* __restrict__ wout, const float* __restrict__ wf,
    short* __restrict__ xb, short* __restrict__ wqb,
    short* __restrict__ wob, short* __restrict__ wfb) {
  const long n_x = (long)M_ROWS * E_DIM;          // 33554432
  const long n_wq = 3L * E_DIM * E_DIM;           // 3145728
  const long n_wo = (long)E_DIM * E_DIM;          // 1048576
  long idx = ((long)blockIdx.x * 256 + threadIdx.x) * 4;
  const float* src;
  short* dst;
  if (idx < n_x) {
    src = x + idx; dst = xb + idx;
  } else if ((idx -= n_x) < n_wq) {
    src = wqkv + idx; dst = wqb + idx;
  } else if ((idx -= n_wq) < n_wo) {
    src = wout + idx; dst = wob + idx;
  } else {
    idx -= n_wo;  // w_f: 4096 elements
    src = wf + idx; dst = wfb + idx;
  }
  float4 v = *(const float4*)src;
  short4 o;
  o.x = f2bf(v.x); o.y = f2bf(v.y); o.z = f2bf(v.z); o.w = f2bf(v.w);
  *(short4*)dst = o;
}

// ---------------------------------------------------------------------------
// K2/K6: 256x256 tile, 8 waves (2x4, each owns 128x64 output), BK=32,
// 4-deep LDS ring (A,B each 4x16KiB = 128KiB total), 3-tile staging
// lookahead with counted s_waitcnt vmcnt(8) at tile boundaries (never 0 in
// the main loop), global_load_lds width-16, setprio(1) around MFMA clusters,
// XCD-aware block swizzle (nwg % 8 == 0 for both call sites).
//
// Bank swizzle (rule #21 both-sides-or-neither): at 64B row stride
// the LINEAR ds_read_b128 pattern has lanes c=0..15 (fixed q) on only 2 of
// 8 16B slot positions -> 8-way batch aliasing. Slot involution
//   slot' = slot ^ ((row>>1)&3)    (XOR addr bits 4-5 with row bits 1-2)
// applied on BOTH sides:
//   - staging source (LDS dest stays linear for global_load_lds, m104):
//       scolb = ((t&3) ^ ((t>>3)&3)) << 4         [(row>>1)&3 == (t>>3)&3]
//   - fragment read:  qs = q ^ ((c>>1)&3)         [(row>>1)&3 == (c>>1)&3
//       for all A/B fragment rows: wm*128, wn*64, mi*16 all == 0 mod 8]
// => any 16-lane batch covers all 32 banks exactly 2x (free, m136). Both
// XORs are per-thread constants: zero loop cost.
//
// Race-freedom: while computing tile t (slot t&3) we stage tile t+3 into
// slot (t+3)&3 = (t-1)&3, whose last reader finished before the t-1 -> t
// boundary barrier. RAW: vmcnt(8) at each boundary leaves exactly the 8
// loads of tiles t+2,t+3 in flight; everything for tile t+1 is complete.
// Tail keeps counts uniform by re-staging tile NT-1 (dup loads, dead slots).
// Hang-safety: barrier count is wave-uniform (NT uniform, no divergent
// exits); counted s_waitcnt is always satisfiable; bounds desk-verified.
// ---------------------------------------------------------------------------
template <int OUT_F32>
__global__ __launch_bounds__(512, 2) void gemm256(
    const short* __restrict__ A, const short* __restrict__ Bm,
    void* __restrict__ Cout, const float* __restrict__ bias, int N, int K) {
  __shared__ short As[4 * 8192];  // 4 slots x (256 rows x 32 cols) = 64 KiB
  __shared__ short Bs[4 * 8192];
  const int t = threadIdx.x;
  const int w = t >> 6, l = t & 63;
  const int q = l >> 4, c = l & 15;
  const int wm = w >> 2, wn = w & 3;  // 2 x 4 wave grid

  // XCD-aware bijective swizzle (nwg % 8 == 0), then column-major tiling so
  // consecutive logical ids within an XCD share the same B-panel (L2 reuse).
  const int nwg = gridDim.x;
  const int cpx = nwg >> 3;
  const int lid = ((int)blockIdx.x & 7) * cpx + ((int)blockIdx.x >> 3);
  const int bm = (lid & 127) << 8;  // M = 32768 fixed -> 128 row-blocks
  const int bn = (lid >> 7) << 8;

  // Staging: per K-tile, A = 256 rows x 64 B = 2 chunks of 8 KiB
  // (128 rows each); thread t covers row t>>2; source col-byte is the
  // swizzled slot (see header comment).
  const long Kb = (long)K * 2;
  const int srow = t >> 2;
  const int scolb = (((t & 3) ^ ((t >> 3) & 3)) << 4);
  const char* gA = (const char*)A + (long)(bm + srow) * Kb + scolb;
  const char* gB = (const char*)Bm + (long)(bn + srow) * Kb + scolb;
  const long chb = 128 * Kb;  // +128 rows (second chunk)
  char* lA = (char*)As + (w << 10);  // wave-uniform LDS base (+lane*16 in HW)
  char* lB = (char*)Bs + (w << 10);

  // Fragment read bases (shorts): row = (wm*128 | wn*64) + mi*16 + c,
  // k-slot swizzled: qs = q ^ ((c>>1)&3).
  const int qs = q ^ ((c >> 1) & 3);
  const short* ar = As + ((wm << 7) + c) * 32 + (qs << 3);
  const short* br = Bs + ((wn << 6) + c) * 32 + (qs << 3);

  f32x4 acc[8][4];
#pragma unroll
  for (int i = 0; i < 8; i++)
#pragma unroll
    for (int j = 0; j < 4; j++) acc[i][j] = (f32x4){0.f, 0.f, 0.f, 0.f};

  // Prologue: stage tiles 0,1,2 into slots 0,1,2 (12 loads), wait for tile 0.
#pragma unroll
  for (int p = 0; p < 3; p++) {
    const char* sa = gA + (long)p * 64;
    const char* sb = gB + (long)p * 64;
    char* da = lA + p * 16384;
    char* db = lB + p * 16384;
    gl_lds16(sa, da);
    gl_lds16(sa + chb, da + 8192);
    gl_lds16(sb, db);
    gl_lds16(sb + chb, db + 8192);
  }
  asm volatile("s_waitcnt vmcnt(8)\n\ts_barrier" ::: "memory");

  const int NT = K >> 5;
  for (int tt = 0; tt < NT; ++tt) {
    const int slot = (tt & 3) * 8192;          // shorts
    const int pslot = ((tt + 3) & 3) * 16384;  // bytes
    const int pkt = (tt + 3 < NT) ? tt + 3 : NT - 1;  // tail: dup-stage
    const short* ap = ar + slot;
    const short* bp = br + slot;
    const char* sa = gA + (long)pkt * 64;
    const char* sb = gB + (long)pkt * 64;

    bf16x8 af[8], bfr[4];
    // ---- phase 1: ds_read half the frags || stage A(t+3) || MFMA mi 0..3
#pragma unroll
    for (int mi = 0; mi < 4; mi++) af[mi] = *(const bf16x8*)(ap + mi * 512);
#pragma unroll
    for (int ni = 0; ni < 4; ni++) bfr[ni] = *(const bf16x8*)(bp + ni * 512);
    gl_lds16(sa, lA + pslot);
    gl_lds16(sa + chb, lA + pslot + 8192);
    __builtin_amdgcn_s_barrier();
    __builtin_amdgcn_s_setprio(1);
#pragma unroll
    for (int mi = 0; mi < 4; mi++)
#pragma unroll
      for (int ni = 0; ni < 4; ni++)
        acc[mi][ni] = MFMA16(af[mi], bfr[ni], acc[mi][ni]);
    __builtin_amdgcn_s_setprio(0);
    __builtin_amdgcn_s_barrier();
    // ---- phase 2: ds_read rest || stage B(t+3) || MFMA mi 4..7
#pragma unroll
    for (int mi = 4; mi < 8; mi++) af[mi] = *(const bf16x8*)(ap + mi * 512);
    gl_lds16(sb, lB + pslot);
    gl_lds16(sb + chb, lB + pslot + 8192);
    __builtin_amdgcn_s_barrier();
    __builtin_amdgcn_s_setprio(1);
#pragma unroll
    for (int mi = 4; mi < 8; mi++)
#pragma unroll
      for (int ni = 0; ni < 4; ni++)
        acc[mi][ni] = MFMA16(af[mi], bfr[ni], acc[mi][ni]);
    __builtin_amdgcn_s_setprio(0);
    // counted boundary wait: tiles <= tt+1 complete, tt+2/tt+3 in flight
    asm volatile("s_waitcnt vmcnt(8)\n\ts_barrier" ::: "memory");
  }
  // drain outstanding gl_lds before LDS dealloc / kernel exit
  asm volatile("s_waitcnt vmcnt(0)" ::: "memory");

  // Epilogue: C/D layout col = c, row = q*4 + r (m89-verified)
  if (OUT_F32) {
    float* C = (float*)Cout;
#pragma unroll
    for (int ni = 0; ni < 4; ni++) {
      int n = bn + (wn << 6) + ni * 16 + c;
      float bo = bias[n];
#pragma unroll
      for (int mi = 0; mi < 8; mi++)
#pragma unroll
        for (int r = 0; r < 4; r++) {
          int m = bm + (wm << 7) + mi * 16 + (q << 2) + r;
          C[(long)m * N + n] = acc[mi][ni][r] + bo;
        }
    }
  } else {
    short* C = (short*)Cout;
#pragma unroll
    for (int ni = 0; ni < 4; ni++) {
      int n = bn + (wn << 6) + ni * 16 + c;
#pragma unroll
      for (int mi = 0; mi < 8; mi++)
#pragma unroll
        for (int r = 0; r < 4; r++) {
          int m = bm + (wm << 7) + mi * 16 + (q << 2) + r;
          C[(long)m * N + n] = f2bf(acc[mi][ni][r]);
        }
    }
  }
}

// ---------------------------------------------------------------------------
// K3: feature map. Per block: (h, b, 256 s rows); wave handles 64 s.
//   Qp[h,b,s,p]  = relu(q . w_f[p] + b_f[p])           (A=q rows, B=w_f rows)
//   KpT[h,b,p,s] = relu(k . w_f[p] + b_f[p])           (A=w_f rows, B=k rows)
//   VT[h,b,d,s]  = v[s,d]                              (A=identity, B=v rows)
// ---------------------------------------------------------------------------
__global__ __launch_bounds__(256) void feature_kernel(
    const short* __restrict__ qkv, const short* __restrict__ wfb,
    const float* __restrict__ b_f, short* __restrict__ Qp,
    short* __restrict__ KpT, short* __restrict__ VT) {
  const int bx = blockIdx.x;
  const int sblk = bx & 15, b = (bx >> 4) & 7, h = bx >> 7;
  const int t = threadIdx.x, w = t >> 6, l = t & 63;
  const int q = l >> 4, c = l & 15;
  const int s_base = sblk * 256 + w * 64;
  const int hb = h * 8 + b;

  bf16x8 wf[4][2];
#pragma unroll
  for (int ti = 0; ti < 4; ti++)
#pragma unroll
    for (int kk = 0; kk < 2; kk++)
      wf[ti][kk] = *(const bf16x8*)(wfb + (ti * 16 + c) * 64 + kk * 32 + q * 8);

  float bfc[4];
#pragma unroll
  for (int ni = 0; ni < 4; ni++) bfc[ni] = b_f[ni * 16 + c];

  f32x4 acc[4][4];
  bf16x8 xf[4][2];

  // ---- Phase Q: Qp (s-major) ----
#pragma unroll
  for (int i = 0; i < 4; i++)
#pragma unroll
    for (int j = 0; j < 4; j++) acc[i][j] = (f32x4){0.f, 0.f, 0.f, 0.f};
#pragma unroll
  for (int mi = 0; mi < 4; mi++) {
    long ridx = (long)((s_base + mi * 16 + c) * 8 + b) * N_QKV;
#pragma unroll
    for (int kk = 0; kk < 2; kk++)
      xf[mi][kk] = *(const bf16x8*)(qkv + ridx + h * 64 + kk * 32 + q * 8);
  }
#pragma unroll
  for (int kk = 0; kk < 2; kk++)
#pragma unroll
    for (int mi = 0; mi < 4; mi++)
#pragma unroll
      for (int ni = 0; ni < 4; ni++)
        acc[mi][ni] = MFMA16(xf[mi][kk], wf[ni][kk], acc[mi][ni]);
#pragma unroll
  for (int mi = 0; mi < 4; mi++)
#pragma unroll
    for (int ni = 0; ni < 4; ni++)
#pragma unroll
      for (int r = 0; r < 4; r++) {
        int s = s_base + mi * 16 + q * 4 + r;
        float v = acc[mi][ni][r] + bfc[ni];
        v = fmaxf(v, 0.f);
        Qp[((long)hb * S_LEN + s) * 64 + ni * 16 + c] = f2bf(v);
      }

  // ---- Phase K: KpT (p-major) via operand swap ----
#pragma unroll
  for (int i = 0; i < 4; i++)
#pragma unroll
    for (int j = 0; j < 4; j++) acc[i][j] = (f32x4){0.f, 0.f, 0.f, 0.f};
#pragma unroll
  for (int si = 0; si < 4; si++) {
    long ridx = (long)((s_base + si * 16 + c) * 8 + b) * N_QKV;
#pragma unroll
    for (int kk = 0; kk < 2; kk++)
      xf[si][kk] =
          *(const bf16x8*)(qkv + ridx + E_DIM + h * 64 + kk * 32 + q * 8);
  }
#pragma unroll
  for (int kk = 0; kk < 2; kk++)
#pragma unroll
    for (int pi = 0; pi < 4; pi++)
#pragma unroll
      for (int si = 0; si < 4; si++)
        acc[pi][si] = MFMA16(wf[pi][kk], xf[si][kk], acc[pi][si]);
#pragma unroll
  for (int pi = 0; pi < 4; pi++)
#pragma unroll
    for (int r = 0; r < 4; r++) {
      int p = pi * 16 + q * 4 + r;
      float bb = b_f[p];
#pragma unroll
      for (int si = 0; si < 4; si++) {
        int s = s_base + si * 16 + c;
        float v = acc[pi][si][r] + bb;
        v = fmaxf(v, 0.f);
        KpT[((long)hb * 64 + p) * S_LEN + s] = f2bf(v);
      }
    }

  // ---- Phase V: VT (d-major) via identity-A MFMA (exact passthrough) ----
  bf16x8 id0 = {0, 0, 0, 0, 0, 0, 0, 0}, id1 = {0, 0, 0, 0, 0, 0, 0, 0};
#pragma unroll
  for (int j = 0; j < 8; j++) {
    int k = q * 8 + j;
    id0[j] = (short)((k == c) ? 0x3F80 : 0);
    id1[j] = (short)((k == c + 16) ? 0x3F80 : 0);
  }
#pragma unroll
  for (int i = 0; i < 4; i++)
#pragma unroll
    for (int j = 0; j < 4; j++) acc[i][j] = (f32x4){0.f, 0.f, 0.f, 0.f};
#pragma unroll
  for (int si = 0; si < 4; si++) {
    long ridx = (long)((s_base + si * 16 + c) * 8 + b) * N_QKV;
#pragma unroll
    for (int kc = 0; kc < 2; kc++)
      xf[si][kc] =
          *(const bf16x8*)(qkv + ridx + 2 * E_DIM + h * 64 + kc * 32 + q * 8);
  }
#pragma unroll
  for (int kc = 0; kc < 2; kc++)
#pragma unroll
    for (int si = 0; si < 4; si++) {
      acc[kc * 2 + 0][si] = MFMA16(id0, xf[si][kc], acc[kc * 2 + 0][si]);
      acc[kc * 2 + 1][si] = MFMA16(id1, xf[si][kc], acc[kc * 2 + 1][si]);
    }
#pragma unroll
  for (int dt = 0; dt < 4; dt++)
#pragma unroll
    for (int si = 0; si < 4; si++)
#pragma unroll
      for (int r = 0; r < 4; r++) {
        int d = (dt >> 1) * 32 + (dt & 1) * 16 + q * 4 + r;
        int s = s_base + si * 16 + c;
        VT[((long)hb * 64 + d) * S_LEN + s] = f2bf(acc[dt][si][r]);
      }
}

// ---------------------------------------------------------------------------
// K4: kv (stored transposed: kvT[d][p] = sum_s v[s,d]*k_p[s,p]), fp32 atomics.
// ---------------------------------------------------------------------------
__global__ __launch_bounds__(256) void kv_kernel(const short* __restrict__ KpT,
                                                 const short* __restrict__ VT,
                                                 float* __restrict__ kvf) {
  const int hb = blockIdx.y, sc = blockIdx.x;
  const int t = threadIdx.x, w = t >> 6, l = t & 63;
  const int q = l >> 4, c = l & 15;
  const int s0 = sc * 512 + w * 128;
  const short* vb = VT + (long)hb * 64 * S_LEN;
  const short* kb = KpT + (long)hb * 64 * S_LEN;

  f32x4 acc[4][4];
#pragma unroll
  for (int i = 0; i < 4; i++)
#pragma unroll
    for (int j = 0; j < 4; j++) acc[i][j] = (f32x4){0.f, 0.f, 0.f, 0.f};

  for (int it = 0; it < 4; it++) {
    int so = s0 + it * 32 + q * 8;
    bf16x8 af[4], bfr[4];
#pragma unroll
    for (int di = 0; di < 4; di++)
      af[di] = *(const bf16x8*)(vb + (long)(di * 16 + c) * S_LEN + so);
#pragma unroll
    for (int pi = 0; pi < 4; pi++)
      bfr[pi] = *(const bf16x8*)(kb + (long)(pi * 16 + c) * S_LEN + so);
#pragma unroll
    for (int di = 0; di < 4; di++)
#pragma unroll
      for (int pi = 0; pi < 4; pi++)
        acc[di][pi] = MFMA16(af[di], bfr[pi], acc[di][pi]);
  }

  __shared__ float red[4][4096];
#pragma unroll
  for (int di = 0; di < 4; di++)
#pragma unroll
    for (int pi = 0; pi < 4; pi++)
#pragma unroll
      for (int r = 0; r < 4; r++)
        red[w][(di * 16 + q * 4 + r) * 64 + pi * 16 + c] = acc[di][pi][r];
  __syncthreads();
  float* dst = kvf + (long)hb * 4096;
  for (int i = 0; i < 16; i++) {
    int idx = i * 256 + t;
    float s = red[0][idx] + red[1][idx] + red[2][idx] + red[3][idx];
    atomicAdd(dst + idx, s);
  }
}

__global__ __launch_bounds__(256) void kv_cast(const float* __restrict__ kvf,
                                               short* __restrict__ kvb) {
  int i = blockIdx.x * 256 + threadIdx.x;  // 524288 total
  kvb[i] = f2bf(kvf[i]);
}

// K4c: k_sum[hb][p] = sum_s KpT[hb][p][s], stored bf16
__global__ __launch_bounds__(256) void ksum_kernel(const short* __restrict__ KpT,
                                                   short* __restrict__ ksum) {
  const int hb = blockIdx.x;
  const int t = threadIdx.x, w = t >> 6, l = t & 63;
  for (int pi = 0; pi < 16; pi++) {
    int p = w * 16 + pi;
    const short* row = KpT + ((long)hb * 64 + p) * S_LEN;
    float s = 0.f;
#pragma unroll
    for (int i = 0; i < 8; i++) {
      bf16x8 v = *(const bf16x8*)(row + i * 512 + l * 8);
#pragma unroll
      for (int j = 0; j < 8; j++) s += bf2f(v[j]);
    }
    for (int off = 32; off > 0; off >>= 1) s += __shfl_down(s, off, 64);
    if (l == 0) ksum[hb * 64 + p] = f2bf(s);
  }
}

// ---------------------------------------------------------------------------
// K5: num = Qp @ kvT^T (K=64), norm via masked-b_frag MFMA column, divide,
// write attn into (S,B,E) bf16 layout.
// ---------------------------------------------------------------------------
__global__ __launch_bounds__(256) void attn_kernel(
    const short* __restrict__ Qp, const short* __restrict__ kvb,
    const short* __restrict__ ksum, short* __restrict__ attn) {
  const int bx = blockIdx.x;
  const int sblk = bx & 15, b = (bx >> 4) & 7, h = bx >> 7;
  const int t = threadIdx.x, w = t >> 6, l = t & 63;
  const int q = l >> 4, c = l & 15;
  const int s_base = sblk * 256 + w * 64;
  const int hb = h * 8 + b;

  bf16x8 bkv[4][2];
#pragma unroll
  for (int ni = 0; ni < 4; ni++)
#pragma unroll
    for (int kk = 0; kk < 2; kk++)
      bkv[ni][kk] = *(const bf16x8*)(kvb + (long)hb * 4096 +
                                     (ni * 16 + c) * 64 + kk * 32 + q * 8);
  bf16x8 bn[2];
  const bf16x8 zfrag = {0, 0, 0, 0, 0, 0, 0, 0};
#pragma unroll
  for (int kk = 0; kk < 2; kk++) {
    bf16x8 v = *(const bf16x8*)(ksum + hb * 64 + kk * 32 + q * 8);
    bn[kk] = (c == 0) ? v : zfrag;
  }

  bf16x8 af[4][2];
#pragma unroll
  for (int mi = 0; mi < 4; mi++)
#pragma unroll
    for (int kk = 0; kk < 2; kk++)
      af[mi][kk] = *(const bf16x8*)(Qp + ((long)hb * S_LEN + s_base + mi * 16 + c) * 64 +
                                    kk * 32 + q * 8);

  f32x4 acc[4][4], accn[4];
#pragma unroll
  for (int i = 0; i < 4; i++) {
    accn[i] = (f32x4){0.f, 0.f, 0.f, 0.f};
#pragma unroll
    for (int j = 0; j < 4; j++) acc[i][j] = (f32x4){0.f, 0.f, 0.f, 0.f};
  }
#pragma unroll
  for (int kk = 0; kk < 2; kk++)
#pragma unroll
    for (int mi = 0; mi < 4; mi++) {
      accn[mi] = MFMA16(af[mi][kk], bn[kk], accn[mi]);
#pragma unroll
      for (int ni = 0; ni < 4; ni++)
        acc[mi][ni] = MFMA16(af[mi][kk], bkv[ni][kk], acc[mi][ni]);
    }

#pragma unroll
  for (int mi = 0; mi < 4; mi++)
#pragma unroll
    for (int r = 0; r < 4; r++) {
      float nv = __shfl(accn[mi][r], l & 48, 64);  // col-0 lane of this quad
      float inv = 1.f / (nv + 1e-8f);
      int s = s_base + mi * 16 + q * 4 + r;
#pragma unroll
      for (int ni = 0; ni < 4; ni++) {
        float v = acc[mi][ni][r] * inv;
        attn[((long)s * 8 + b) * E_DIM + h * 64 + ni * 16 + c] = f2bf(v);
      }
    }
}

// ---------------------------------------------------------------------------
// Launch
// ---------------------------------------------------------------------------
extern "C" void kernel_launch(void* const* d_in, const int* in_sizes, int n_in,
                              void* d_out, int out_size, void* d_ws,
                              size_t ws_size, hipStream_t stream) {
  const float* x = (const float*)d_in[0];
  const float* w_qkv = (const float*)d_in[1];
  const float* w_out = (const float*)d_in[2];
  const float* b_out = (const float*)d_in[3];
  const float* w_f = (const float*)d_in[4];
  const float* b_f = (const float*)d_in[5];

  char* ws = (char*)d_ws;
  // workspace layout (bytes); total ~459 MiB
  constexpr size_t off_xb = 0;                       // 64 MB (aliased by attn)
  constexpr size_t off_wqb = 67108864;               // 6 MB
  constexpr size_t off_wob = off_wqb + 6291456;      // 2 MB
  constexpr size_t off_wfb = off_wob + 2097152;      // 8 KB
  constexpr size_t off_qkv = off_wfb + 8192;         // 192 MB
  constexpr size_t off_Qp = off_qkv + 201326592;     // 64 MB
  constexpr size_t off_KpT = off_Qp + 67108864;      // 64 MB
  constexpr size_t off_VT = off_KpT + 67108864;      // 64 MB
  constexpr size_t off_kvf = off_VT + 67108864;      // 2 MB
  constexpr size_t off_kvb = off_kvf + 2097152;      // 1 MB
  constexpr size_t off_ksum = off_kvb + 1048576;     // 16 KB

  short* xb = (short*)(ws + off_xb);
  short* wqb = (short*)(ws + off_wqb);
  short* wob = (short*)(ws + off_wob);
  short* wfb = (short*)(ws + off_wfb);
  short* qkv = (short*)(ws + off_qkv);
  short* Qp = (short*)(ws + off_Qp);
  short* KpT = (short*)(ws + off_KpT);
  short* VT = (short*)(ws + off_VT);
  float* kvf = (float*)(ws + off_kvf);
  short* kvb = (short*)(ws + off_kvb);
  short* ksum = (short*)(ws + off_ksum);
  short* attn = xb;  // alias: xb dead after QKV GEMM

  // K1: casts (37752832 elements / 4 per thread)
  cast_all<<<36868, 256, 0, stream>>>(x, w_qkv, w_out, w_f, xb, wqb, wob, wfb);

  // K2: qkv = xb @ wqb^T  (M=32768, N=3072, K=1024); 128x12 = 1536 blocks
  gemm256<0><<<1536, 512, 0, stream>>>(xb, wqb, qkv, nullptr, N_QKV, E_DIM);

  // K3: feature maps + transposes
  feature_kernel<<<2048, 256, 0, stream>>>(qkv, wfb, b_f, Qp, KpT, VT);

  // K4: kv accumulation (zero-init kv first; ws is poisoned each call)
  hipMemsetAsync(kvf, 0, (size_t)HB_DIM * 4096 * 4, stream);
  kv_kernel<<<dim3(8, HB_DIM), 256, 0, stream>>>(KpT, VT, kvf);
  kv_cast<<<2048, 256, 0, stream>>>(kvf, kvb);
  ksum_kernel<<<HB_DIM, 256, 0, stream>>>(KpT, ksum);

  // K5: attn = (Qp @ kv) / (Qp . ksum), into (S,B,E) bf16
  attn_kernel<<<2048, 256, 0, stream>>>(Qp, kvb, ksum, attn);

  // K6: out = attn @ w_out^T + b_out  (fp32); 128x4 = 512 blocks
  gemm256<1><<<512, 512, 0, stream>>>(attn, wob, (float*)d_out, b_out,
                                      E_DIM, E_DIM);
}

// Round 9
// 736.357 us; speedup vs baseline: 1.1715x; 1.1715x over previous
//
#include <hip/hip_runtime.h>
#include <hip/hip_bf16.h>
#include <stdint.h>

// Problem constants
#define S_LEN 4096
#define B_DIM 8
#define E_DIM 1024
#define H_DIM 16
#define M_ROWS (S_LEN * B_DIM)   // 32768
#define N_QKV (3 * E_DIM)        // 3072
#define HB_DIM (H_DIM * B_DIM)   // 128

typedef float f32x4 __attribute__((ext_vector_type(4)));
typedef short bf16x8 __attribute__((ext_vector_type(8)));

#define MFMA16(a, b, c) __builtin_amdgcn_mfma_f32_16x16x32_bf16(a, b, c, 0, 0, 0)

__device__ __forceinline__ short f2bf(float f) {
  __hip_bfloat16 h = __float2bfloat16(f);
  short s;
  __builtin_memcpy(&s, &h, 2);
  return s;
}
__device__ __forceinline__ float bf2f(short b) {
  unsigned u = ((unsigned)(unsigned short)b) << 16;
  float f;
  __builtin_memcpy(&f, &u, 4);
  return f;
}
__device__ __forceinline__ void gl_lds16(const void* g, void* l) {
  __builtin_amdgcn_global_load_lds(
      (const __attribute__((address_space(1))) void*)g,
      (__attribute__((address_space(3))) void*)l, 16, 0, 0);
}

// ---------------------------------------------------------------------------
// K1: cast fp32 -> bf16 for x, w_qkv, w_out, w_f (one thread = 4 elements)
// ---------------------------------------------------------------------------
__global__ __launch_bounds__(256) void cast_all(
    const float* __restrict__ x, const float* __restrict__ wqkv,
    const float* __restrict__ wout, const float* __restrict__ wf,
    short* __restrict__ xb, short* __restrict__ wqb,
    short* __restrict__ wob, short* __restrict__ wfb) {
  const long n_x = (long)M_ROWS * E_DIM;          // 33554432
  const long n_wq = 3L * E_DIM * E_DIM;           // 3145728
  const long n_wo = (long)E_DIM * E_DIM;          // 1048576
  long idx = ((long)blockIdx.x * 256 + threadIdx.x) * 4;
  const float* src;
  short* dst;
  if (idx < n_x) {
    src = x + idx; dst = xb + idx;
  } else if ((idx -= n_x) < n_wq) {
    src = wqkv + idx; dst = wqb + idx;
  } else if ((idx -= n_wq) < n_wo) {
    src = wout + idx; dst = wob + idx;
  } else {
    idx -= n_wo;  // w_f: 4096 elements
    src = wf + idx; dst = wfb + idx;
  }
  float4 v = *(const float4*)src;
  short4 o;
  o.x = f2bf(v.x); o.y = f2bf(v.y); o.z = f2bf(v.z); o.w = f2bf(v.w);
  *(short4*)dst = o;
}

// ---------------------------------------------------------------------------
// K2/K6 (m201-shape): 256x256 tile, 8 waves (2x4, each 128x64),
// BK=64, double-buffered LDS (A[2][2 halves][128x128B] + B same = 128 KiB).
// Per K-tile: 4 C-quadrant phases, each {ds_read (12 or 4 b128) ; stage one
// half-tile (2 gl_lds) ; barrier ; setprio ; 16 MFMA ; setprio ; barrier}.
// B-fragments (8 b128) read once in phase 0, HELD IN REGISTERS phases 1-3.
// ONE counted s_waitcnt vmcnt(4) per K-tile, fused with the tile-boundary
// barrier (never 0 in the main loop). XCD-aware block swizzle (nwg%8==0).
//
// Bank swizzle (both-sides, rule #21): 128 B row stride => classic 16-way
// conflict on ds_read_b128 (G4). Slot involution  slot' = slot ^ (row&7)
// (8 slots of 16B per row):
//   - staging source: scb = ((t&7) ^ ((t>>3)&7)) << 4   [(t>>3)&7 = row&7]
//     (LDS dest stays LINEAR for global_load_lds, m104)
//   - fragment read:  slot = (kk*4+q) ^ (c&7)           [row&7 == c&7 for
//     all A/B fragment rows: mi*16, ni*16, (wn&1)*64 all == 0 mod 8]
// Enumeration: fixed (mi,kk), lanes (q,c): 8 lanes per slot value, each bank
// touched exactly 8x = wave64/b128 minimum => conflict-free (R5 HW evidence:
// the analogous R2 swizzle measured SQ_LDS_BANK_CONFLICT = 0).
//
// Ledger (per-thread, 2 loads per stage; in-order vmcnt retirement):
//   prologue: A0(0) A1(0) B0(0) B1(0) B0(1) B1(1); vmcnt(4) -> tile-0 halves
//     complete, B(1) outstanding.
//   tile T: ph0 stage A0(T+1); ph1 A1(T+1); ph2 B0(T+2); ph3 B1(T+2);
//     end-of-tile vmcnt(4) retires {B0,B1,A0,A1}(T+1) exactly ->
//     outstanding = B(T+2) = steady state (induction holds).
//   RAW slack: A1 2 phases, A0 3, B 5-6 (> HBM latency at ~700cy/phase).
//   WAR: A-half(T+1) aliases A-half(T-1), last read phase 3 of T-1, stage
//     issued >= 1 barrier later. B(T+2) aliases B(T) [(T+2)&1==T&1], B is
//     read ONLY in phase 0, stage issued in phases 2/3. Tail: src clamped
//     to NT-1, dest keeps TRUE-target parity -> writes land only in
//     finished-or-never-read regions (desk-verified incl. T=NT-2, NT-1;
//     the T=NT-1 B dup-stage writes identical data after reads complete).
// Hang-safety: barrier count wave-uniform; counted waits always satisfiable.
// ---------------------------------------------------------------------------
__device__ __forceinline__ void mma16q(f32x4 acc[8][4], const bf16x8 afr[2][2],
                                       const bf16x8 bfr[4][2], int m0) {
#pragma unroll
  for (int kk = 0; kk < 2; kk++)
#pragma unroll
    for (int ii = 0; ii < 2; ii++)
#pragma unroll
      for (int ni = 0; ni < 4; ni++)
        acc[m0 + ii][ni] = MFMA16(afr[ii][kk], bfr[ni][kk], acc[m0 + ii][ni]);
}

template <int OUT_F32>
__global__ __launch_bounds__(512, 2) void gemm256(
    const short* __restrict__ A, const short* __restrict__ Bm,
    void* __restrict__ Cout, const float* __restrict__ bias, int N, int K) {
  __shared__ short L[65536];  // 128 KiB: A = [buf][half][8192 shorts], B at +32768 shorts
  char* Lb = (char*)L;
  const int t = threadIdx.x;
  const int w = t >> 6, l = t & 63;
  const int q = l >> 4, c = l & 15;
  const int wm = w >> 2, wn = w & 3;  // 2 x 4 wave grid

  // XCD-aware bijective swizzle (nwg % 8 == 0), column-major tiling.
  const int nwg = gridDim.x;
  const int cpx = nwg >> 3;
  const int lid = ((int)blockIdx.x & 7) * cpx + ((int)blockIdx.x >> 3);
  const int bm = (lid & 127) << 8;  // M = 32768 -> 128 row-blocks
  const int bn = (lid >> 7) << 8;

  // Staging: half-tile = 128 rows x 128 B. Thread t: rows (h*2+j)*64 + (t>>3),
  // src slot pre-swizzled; LDS dest linear (wave-uniform base + lane*16).
  const long Kb = (long)K * 2;
  const int srow = t >> 3;  // 0..63
  const int scb = (((t & 7) ^ ((t >> 3) & 7)) << 4);
  const char* gA = (const char*)A + (long)(bm + srow) * Kb + scb;
  const char* gB = (const char*)Bm + (long)(bn + srow) * Kb + scb;
  const long r64 = 64 * Kb;  // 64 rows in bytes

#define STAGE_A(h, srcT, dbuf)                                      \
  do {                                                              \
    const char* s_ = gA + (long)(srcT) * 128 + (long)(h) * 2 * r64; \
    char* d_ = Lb + (dbuf) * 32768 + (h) * 16384 + (w << 10);       \
    gl_lds16(s_, d_);                                               \
    gl_lds16(s_ + r64, d_ + 8192);                                  \
  } while (0)
#define STAGE_B(h, srcT, dbuf)                                      \
  do {                                                              \
    const char* s_ = gB + (long)(srcT) * 128 + (long)(h) * 2 * r64; \
    char* d_ = Lb + 65536 + (dbuf) * 32768 + (h) * 16384 + (w << 10); \
    gl_lds16(s_, d_);                                               \
    gl_lds16(s_ + r64, d_ + 8192);                                  \
  } while (0)

  // Fragment read offsets (shorts). Row stride 64 shorts; slot = 8 shorts.
  const int sw = c & 7;
  const int s0 = (q ^ sw) << 3;       // kk=0: slot (q)^(row&7), *8 shorts
  const int s1 = s0 ^ 32;             // kk=1: slot (4+q)^(row&7)
  const int aoff = wm * 8192 + c * 64;                        // + buf*16384 + mi*1024 + s
  const int boff = 32768 + (wn >> 1) * 8192 + ((wn & 1) * 64 + c) * 64;  // + buf*16384 + ni*1024 + s

#define LDA(dst, mi, kk) \
  dst = *(const bf16x8*)(L + bufo + aoff + (mi) * 1024 + ((kk) ? s1 : s0))
#define LDB(dst, ni, kk) \
  dst = *(const bf16x8*)(L + bufo + boff + (ni) * 1024 + ((kk) ? s1 : s0))

  f32x4 acc[8][4];
#pragma unroll
  for (int i = 0; i < 8; i++)
#pragma unroll
    for (int j = 0; j < 4; j++) acc[i][j] = (f32x4){0.f, 0.f, 0.f, 0.f};

  const int NT = K >> 6;  // K-tiles of 64 (K=1024 -> 16)

  // Prologue: tile-0 A+B halves, then tile-1 B halves (12 loads).
  STAGE_A(0, 0, 0);
  STAGE_A(1, 0, 0);
  STAGE_B(0, 0, 0);
  STAGE_B(1, 0, 0);
  STAGE_B(0, 1, 1);
  STAGE_B(1, 1, 1);
  asm volatile("s_waitcnt vmcnt(4)\n\ts_barrier" ::: "memory");

  for (int T = 0; T < NT; ++T) {
    const int bufo = (T & 1) * 16384;            // shorts
    const int TA = (T + 1 < NT) ? T + 1 : NT - 1;  // src clamp (tail dup)
    const int TB = (T + 2 < NT) ? T + 2 : NT - 1;
    const int bufA = (T + 1) & 1;                // TRUE-target dest parity
    const int bufB = T & 1;                      // (T+2)&1 == T&1

    bf16x8 bfr[4][2], afr[2][2];

    // ---- phase 0: B all (8) + A mi0,1 (4) ; stage A0(T+1) ; MFMA mi0,1
#pragma unroll
    for (int ni = 0; ni < 4; ni++) {
      LDB(bfr[ni][0], ni, 0);
      LDB(bfr[ni][1], ni, 1);
    }
    LDA(afr[0][0], 0, 0); LDA(afr[0][1], 0, 1);
    LDA(afr[1][0], 1, 0); LDA(afr[1][1], 1, 1);
    STAGE_A(0, TA, bufA);
    __builtin_amdgcn_s_barrier();
    __builtin_amdgcn_s_setprio(1);
    mma16q(acc, afr, bfr, 0);
    __builtin_amdgcn_s_setprio(0);
    __builtin_amdgcn_s_barrier();

    // ---- phase 1: A mi2,3 ; stage A1(T+1) ; MFMA mi2,3
    LDA(afr[0][0], 2, 0); LDA(afr[0][1], 2, 1);
    LDA(afr[1][0], 3, 0); LDA(afr[1][1], 3, 1);
    STAGE_A(1, TA, bufA);
    __builtin_amdgcn_s_barrier();
    __builtin_amdgcn_s_setprio(1);
    mma16q(acc, afr, bfr, 2);
    __builtin_amdgcn_s_setprio(0);
    __builtin_amdgcn_s_barrier();

    // ---- phase 2: A mi4,5 ; stage B0(T+2) ; MFMA mi4,5
    LDA(afr[0][0], 4, 0); LDA(afr[0][1], 4, 1);
    LDA(afr[1][0], 5, 0); LDA(afr[1][1], 5, 1);
    STAGE_B(0, TB, bufB);
    __builtin_amdgcn_s_barrier();
    __builtin_amdgcn_s_setprio(1);
    mma16q(acc, afr, bfr, 4);
    __builtin_amdgcn_s_setprio(0);
    __builtin_amdgcn_s_barrier();

    // ---- phase 3: A mi6,7 ; stage B1(T+2) ; MFMA mi6,7 ; boundary vmcnt
    LDA(afr[0][0], 6, 0); LDA(afr[0][1], 6, 1);
    LDA(afr[1][0], 7, 0); LDA(afr[1][1], 7, 1);
    STAGE_B(1, TB, bufB);
    __builtin_amdgcn_s_barrier();
    __builtin_amdgcn_s_setprio(1);
    mma16q(acc, afr, bfr, 6);
    __builtin_amdgcn_s_setprio(0);
    // counted boundary wait: tile T+1's 4 halves retired; B(T+2) in flight
    asm volatile("s_waitcnt vmcnt(4)\n\ts_barrier" ::: "memory");
  }
  // drain outstanding gl_lds before LDS dealloc / kernel exit
  asm volatile("s_waitcnt vmcnt(0)" ::: "memory");

#undef STAGE_A
#undef STAGE_B
#undef LDA
#undef LDB

  // Epilogue: C/D layout col = c, row = q*4 + r (m89-verified)
  if (OUT_F32) {
    float* C = (float*)Cout;
#pragma unroll
    for (int ni = 0; ni < 4; ni++) {
      int n = bn + (wn << 6) + ni * 16 + c;
      float bo = bias[n];
#pragma unroll
      for (int mi = 0; mi < 8; mi++)
#pragma unroll
        for (int r = 0; r < 4; r++) {
          int m = bm + (wm << 7) + mi * 16 + (q << 2) + r;
          C[(long)m * N + n] = acc[mi][ni][r] + bo;
        }
    }
  } else {
    short* C = (short*)Cout;
#pragma unroll
    for (int ni = 0; ni < 4; ni++) {
      int n = bn + (wn << 6) + ni * 16 + c;
#pragma unroll
      for (int mi = 0; mi < 8; mi++)
#pragma unroll
        for (int r = 0; r < 4; r++) {
          int m = bm + (wm << 7) + mi * 16 + (q << 2) + r;
          C[(long)m * N + n] = f2bf(acc[mi][ni][r]);
        }
    }
  }
}

// ---------------------------------------------------------------------------
// K3: feature map. Per block: (h, b, 256 s rows); wave handles 64 s.
//   Qp[h,b,s,p]  = relu(q . w_f[p] + b_f[p])           (A=q rows, B=w_f rows)
//   KpT[h,b,p,s] = relu(k . w_f[p] + b_f[p])           (A=w_f rows, B=k rows)
//   VT[h,b,d,s]  = v[s,d]                              (A=identity, B=v rows)
// ---------------------------------------------------------------------------
__global__ __launch_bounds__(256) void feature_kernel(
    const short* __restrict__ qkv, const short* __restrict__ wfb,
    const float* __restrict__ b_f, short* __restrict__ Qp,
    short* __restrict__ KpT, short* __restrict__ VT) {
  const int bx = blockIdx.x;
  const int sblk = bx & 15, b = (bx >> 4) & 7, h = bx >> 7;
  const int t = threadIdx.x, w = t >> 6, l = t & 63;
  const int q = l >> 4, c = l & 15;
  const int s_base = sblk * 256 + w * 64;
  const int hb = h * 8 + b;

  bf16x8 wf[4][2];
#pragma unroll
  for (int ti = 0; ti < 4; ti++)
#pragma unroll
    for (int kk = 0; kk < 2; kk++)
      wf[ti][kk] = *(const bf16x8*)(wfb + (ti * 16 + c) * 64 + kk * 32 + q * 8);

  float bfc[4];
#pragma unroll
  for (int ni = 0; ni < 4; ni++) bfc[ni] = b_f[ni * 16 + c];

  f32x4 acc[4][4];
  bf16x8 xf[4][2];

  // ---- Phase Q: Qp (s-major) ----
#pragma unroll
  for (int i = 0; i < 4; i++)
#pragma unroll
    for (int j = 0; j < 4; j++) acc[i][j] = (f32x4){0.f, 0.f, 0.f, 0.f};
#pragma unroll
  for (int mi = 0; mi < 4; mi++) {
    long ridx = (long)((s_base + mi * 16 + c) * 8 + b) * N_QKV;
#pragma unroll
    for (int kk = 0; kk < 2; kk++)
      xf[mi][kk] = *(const bf16x8*)(qkv + ridx + h * 64 + kk * 32 + q * 8);
  }
#pragma unroll
  for (int kk = 0; kk < 2; kk++)
#pragma unroll
    for (int mi = 0; mi < 4; mi++)
#pragma unroll
      for (int ni = 0; ni < 4; ni++)
        acc[mi][ni] = MFMA16(xf[mi][kk], wf[ni][kk], acc[mi][ni]);
#pragma unroll
  for (int mi = 0; mi < 4; mi++)
#pragma unroll
    for (int ni = 0; ni < 4; ni++)
#pragma unroll
      for (int r = 0; r < 4; r++) {
        int s = s_base + mi * 16 + q * 4 + r;
        float v = acc[mi][ni][r] + bfc[ni];
        v = fmaxf(v, 0.f);
        Qp[((long)hb * S_LEN + s) * 64 + ni * 16 + c] = f2bf(v);
      }

  // ---- Phase K: KpT (p-major) via operand swap ----
#pragma unroll
  for (int i = 0; i < 4; i++)
#pragma unroll
    for (int j = 0; j < 4; j++) acc[i][j] = (f32x4){0.f, 0.f, 0.f, 0.f};
#pragma unroll
  for (int si = 0; si < 4; si++) {
    long ridx = (long)((s_base + si * 16 + c) * 8 + b) * N_QKV;
#pragma unroll
    for (int kk = 0; kk < 2; kk++)
      xf[si][kk] =
          *(const bf16x8*)(qkv + ridx + E_DIM + h * 64 + kk * 32 + q * 8);
  }
#pragma unroll
  for (int kk = 0; kk < 2; kk++)
#pragma unroll
    for (int pi = 0; pi < 4; pi++)
#pragma unroll
      for (int si = 0; si < 4; si++)
        acc[pi][si] = MFMA16(wf[pi][kk], xf[si][kk], acc[pi][si]);
#pragma unroll
  for (int pi = 0; pi < 4; pi++)
#pragma unroll
    for (int r = 0; r < 4; r++) {
      int p = pi * 16 + q * 4 + r;
      float bb = b_f[p];
#pragma unroll
      for (int si = 0; si < 4; si++) {
        int s = s_base + si * 16 + c;
        float v = acc[pi][si][r] + bb;
        v = fmaxf(v, 0.f);
        KpT[((long)hb * 64 + p) * S_LEN + s] = f2bf(v);
      }
    }

  // ---- Phase V: VT (d-major) via identity-A MFMA (exact passthrough) ----
  bf16x8 id0 = {0, 0, 0, 0, 0, 0, 0, 0}, id1 = {0, 0, 0, 0, 0, 0, 0, 0};
#pragma unroll
  for (int j = 0; j < 8; j++) {
    int k = q * 8 + j;
    id0[j] = (short)((k == c) ? 0x3F80 : 0);
    id1[j] = (short)((k == c + 16) ? 0x3F80 : 0);
  }
#pragma unroll
  for (int i = 0; i < 4; i++)
#pragma unroll
    for (int j = 0; j < 4; j++) acc[i][j] = (f32x4){0.f, 0.f, 0.f, 0.f};
#pragma unroll
  for (int si = 0; si < 4; si++) {
    long ridx = (long)((s_base + si * 16 + c) * 8 + b) * N_QKV;
#pragma unroll
    for (int kc = 0; kc < 2; kc++)
      xf[si][kc] =
          *(const bf16x8*)(qkv + ridx + 2 * E_DIM + h * 64 + kc * 32 + q * 8);
  }
#pragma unroll
  for (int kc = 0; kc < 2; kc++)
#pragma unroll
    for (int si = 0; si < 4; si++) {
      acc[kc * 2 + 0][si] = MFMA16(id0, xf[si][kc], acc[kc * 2 + 0][si]);
      acc[kc * 2 + 1][si] = MFMA16(id1, xf[si][kc], acc[kc * 2 + 1][si]);
    }
#pragma unroll
  for (int dt = 0; dt < 4; dt++)
#pragma unroll
    for (int si = 0; si < 4; si++)
#pragma unroll
      for (int r = 0; r < 4; r++) {
        int d = (dt >> 1) * 32 + (dt & 1) * 16 + q * 4 + r;
        int s = s_base + si * 16 + c;
        VT[((long)hb * 64 + d) * S_LEN + s] = f2bf(acc[dt][si][r]);
      }
}

// ---------------------------------------------------------------------------
// K4: kv (stored transposed: kvT[d][p] = sum_s v[s,d]*k_p[s,p]), fp32 atomics.
// ---------------------------------------------------------------------------
__global__ __launch_bounds__(256) void kv_kernel(const short* __restrict__ KpT,
                                                 const short* __restrict__ VT,
                                                 float* __restrict__ kvf) {
  const int hb = blockIdx.y, sc = blockIdx.x;
  const int t = threadIdx.x, w = t >> 6, l = t & 63;
  const int q = l >> 4, c = l & 15;
  const int s0 = sc * 512 + w * 128;
  const short* vb = VT + (long)hb * 64 * S_LEN;
  const short* kb = KpT + (long)hb * 64 * S_LEN;

  f32x4 acc[4][4];
#pragma unroll
  for (int i = 0; i < 4; i++)
#pragma unroll
    for (int j = 0; j < 4; j++) acc[i][j] = (f32x4){0.f, 0.f, 0.f, 0.f};

  for (int it = 0; it < 4; it++) {
    int so = s0 + it * 32 + q * 8;
    bf16x8 af[4], bfr[4];
#pragma unroll
    for (int di = 0; di < 4; di++)
      af[di] = *(const bf16x8*)(vb + (long)(di * 16 + c) * S_LEN + so);
#pragma unroll
    for (int pi = 0; pi < 4; pi++)
      bfr[pi] = *(const bf16x8*)(kb + (long)(pi * 16 + c) * S_LEN + so);
#pragma unroll
    for (int di = 0; di < 4; di++)
#pragma unroll
      for (int pi = 0; pi < 4; pi++)
        acc[di][pi] = MFMA16(af[di], bfr[pi], acc[di][pi]);
  }

  __shared__ float red[4][4096];
#pragma unroll
  for (int di = 0; di < 4; di++)
#pragma unroll
    for (int pi = 0; pi < 4; pi++)
#pragma unroll
      for (int r = 0; r < 4; r++)
        red[w][(di * 16 + q * 4 + r) * 64 + pi * 16 + c] = acc[di][pi][r];
  __syncthreads();
  float* dst = kvf + (long)hb * 4096;
  for (int i = 0; i < 16; i++) {
    int idx = i * 256 + t;
    float s = red[0][idx] + red[1][idx] + red[2][idx] + red[3][idx];
    atomicAdd(dst + idx, s);
  }
}

__global__ __launch_bounds__(256) void kv_cast(const float* __restrict__ kvf,
                                               short* __restrict__ kvb) {
  int i = blockIdx.x * 256 + threadIdx.x;  // 524288 total
  kvb[i] = f2bf(kvf[i]);
}

// K4c: k_sum[hb][p] = sum_s KpT[hb][p][s], stored bf16
__global__ __launch_bounds__(256) void ksum_kernel(const short* __restrict__ KpT,
                                                   short* __restrict__ ksum) {
  const int hb = blockIdx.x;
  const int t = threadIdx.x, w = t >> 6, l = t & 63;
  for (int pi = 0; pi < 16; pi++) {
    int p = w * 16 + pi;
    const short* row = KpT + ((long)hb * 64 + p) * S_LEN;
    float s = 0.f;
#pragma unroll
    for (int i = 0; i < 8; i++) {
      bf16x8 v = *(const bf16x8*)(row + i * 512 + l * 8);
#pragma unroll
      for (int j = 0; j < 8; j++) s += bf2f(v[j]);
    }
    for (int off = 32; off > 0; off >>= 1) s += __shfl_down(s, off, 64);
    if (l == 0) ksum[hb * 64 + p] = f2bf(s);
  }
}

// ---------------------------------------------------------------------------
// K5: num = Qp @ kvT^T (K=64), norm via masked-b_frag MFMA column, divide,
// write attn into (S,B,E) bf16 layout.
// ---------------------------------------------------------------------------
__global__ __launch_bounds__(256) void attn_kernel(
    const short* __restrict__ Qp, const short* __restrict__ kvb,
    const short* __restrict__ ksum, short* __restrict__ attn) {
  const int bx = blockIdx.x;
  const int sblk = bx & 15, b = (bx >> 4) & 7, h = bx >> 7;
  const int t = threadIdx.x, w = t >> 6, l = t & 63;
  const int q = l >> 4, c = l & 15;
  const int s_base = sblk * 256 + w * 64;
  const int hb = h * 8 + b;

  bf16x8 bkv[4][2];
#pragma unroll
  for (int ni = 0; ni < 4; ni++)
#pragma unroll
    for (int kk = 0; kk < 2; kk++)
      bkv[ni][kk] = *(const bf16x8*)(kvb + (long)hb * 4096 +
                                     (ni * 16 + c) * 64 + kk * 32 + q * 8);
  bf16x8 bn[2];
  const bf16x8 zfrag = {0, 0, 0, 0, 0, 0, 0, 0};
#pragma unroll
  for (int kk = 0; kk < 2; kk++) {
    bf16x8 v = *(const bf16x8*)(ksum + hb * 64 + kk * 32 + q * 8);
    bn[kk] = (c == 0) ? v : zfrag;
  }

  bf16x8 af[4][2];
#pragma unroll
  for (int mi = 0; mi < 4; mi++)
#pragma unroll
    for (int kk = 0; kk < 2; kk++)
      af[mi][kk] = *(const bf16x8*)(Qp + ((long)hb * S_LEN + s_base + mi * 16 + c) * 64 +
                                    kk * 32 + q * 8);

  f32x4 acc[4][4], accn[4];
#pragma unroll
  for (int i = 0; i < 4; i++) {
    accn[i] = (f32x4){0.f, 0.f, 0.f, 0.f};
#pragma unroll
    for (int j = 0; j < 4; j++) acc[i][j] = (f32x4){0.f, 0.f, 0.f, 0.f};
  }
#pragma unroll
  for (int kk = 0; kk < 2; kk++)
#pragma unroll
    for (int mi = 0; mi < 4; mi++) {
      accn[mi] = MFMA16(af[mi][kk], bn[kk], accn[mi]);
#pragma unroll
      for (int ni = 0; ni < 4; ni++)
        acc[mi][ni] = MFMA16(af[mi][kk], bkv[ni][kk], acc[mi][ni]);
    }

#pragma unroll
  for (int mi = 0; mi < 4; mi++)
#pragma unroll
    for (int r = 0; r < 4; r++) {
      float nv = __shfl(accn[mi][r], l & 48, 64);  // col-0 lane of this quad
      float inv = 1.f / (nv + 1e-8f);
      int s = s_base + mi * 16 + q * 4 + r;
#pragma unroll
      for (int ni = 0; ni < 4; ni++) {
        float v = acc[mi][ni][r] * inv;
        attn[((long)s * 8 + b) * E_DIM + h * 64 + ni * 16 + c] = f2bf(v);
      }
    }
}

// ---------------------------------------------------------------------------
// Launch
// ---------------------------------------------------------------------------
extern "C" void kernel_launch(void* const* d_in, const int* in_sizes, int n_in,
                              void* d_out, int out_size, void* d_ws,
                              size_t ws_size, hipStream_t stream) {
  const float* x = (const float*)d_in[0];
  const float* w_qkv = (const float*)d_in[1];
  const float* w_out = (const float*)d_in[2];
  const float* b_out = (const float*)d_in[3];
  const float* w_f = (const float*)d_in[4];
  const float* b_f = (const float*)d_in[5];

  char* ws = (char*)d_ws;
  // workspace layout (bytes); total ~459 MiB
  constexpr size_t off_xb = 0;                       // 64 MB (aliased by attn)
  constexpr size_t off_wqb = 67108864;               // 6 MB
  constexpr size_t off_wob = off_wqb + 6291456;      // 2 MB
  constexpr size_t off_wfb = off_wob + 2097152;      // 8 KB
  constexpr size_t off_qkv = off_wfb + 8192;         // 192 MB
  constexpr size_t off_Qp = off_qkv + 201326592;     // 64 MB
  constexpr size_t off_KpT = off_Qp + 67108864;      // 64 MB
  constexpr size_t off_VT = off_KpT + 67108864;      // 64 MB
  constexpr size_t off_kvf = off_VT + 67108864;      // 2 MB
  constexpr size_t off_kvb = off_kvf + 2097152;      // 1 MB
  constexpr size_t off_ksum = off_kvb + 1048576;     // 16 KB

  short* xb = (short*)(ws + off_xb);
  short* wqb = (short*)(ws + off_wqb);
  short* wob = (short*)(ws + off_wob);
  short* wfb = (short*)(ws + off_wfb);
  short* qkv = (short*)(ws + off_qkv);
  short* Qp = (short*)(ws + off_Qp);
  short* KpT = (short*)(ws + off_KpT);
  short* VT = (short*)(ws + off_VT);
  float* kvf = (float*)(ws + off_kvf);
  short* kvb = (short*)(ws + off_kvb);
  short* ksum = (short*)(ws + off_ksum);
  short* attn = xb;  // alias: xb dead after QKV GEMM

  // K1: casts (37752832 elements / 4 per thread)
  cast_all<<<36868, 256, 0, stream>>>(x, w_qkv, w_out, w_f, xb, wqb, wob, wfb);

  // K2: qkv = xb @ wqb^T  (M=32768, N=3072, K=1024); 128x12 = 1536 blocks
  gemm256<0><<<1536, 512, 0, stream>>>(xb, wqb, qkv, nullptr, N_QKV, E_DIM);

  // K3: feature maps + transposes
  feature_kernel<<<2048, 256, 0, stream>>>(qkv, wfb, b_f, Qp, KpT, VT);

  // K4: kv accumulation (zero-init kv first; ws is poisoned each call)
  hipMemsetAsync(kvf, 0, (size_t)HB_DIM * 4096 * 4, stream);
  kv_kernel<<<dim3(8, HB_DIM), 256, 0, stream>>>(KpT, VT, kvf);
  kv_cast<<<2048, 256, 0, stream>>>(kvf, kvb);
  ksum_kernel<<<HB_DIM, 256, 0, stream>>>(KpT, ksum);

  // K5: attn = (Qp @ kv) / (Qp . ksum), into (S,B,E) bf16
  attn_kernel<<<2048, 256, 0, stream>>>(Qp, kvb, ksum, attn);

  // K6: out = attn @ w_out^T + b_out  (fp32); 128x4 = 512 blocks
  gemm256<1><<<512, 512, 0, stream>>>(attn, wob, (float*)d_out, b_out,
                                      E_DIM, E_DIM);
}

// Round 10
// 720.355 us; speedup vs baseline: 1.1975x; 1.0222x over previous
//
#include <hip/hip_runtime.h>
#include <hip/hip_bf16.h>
#include <stdint.h>

// Problem constants
#define S_LEN 4096
#define B_DIM 8
#define E_DIM 1024
#define H_DIM 16
#define M_ROWS (S_LEN * B_DIM)   // 32768
#define N_QKV (3 * E_DIM)        // 3072
#define HB_DIM (H_DIM * B_DIM)   // 128

typedef float f32x4 __attribute__((ext_vector_type(4)));
typedef short bf16x8 __attribute__((ext_vector_type(8)));

#define MFMA16(a, b, c) __builtin_amdgcn_mfma_f32_16x16x32_bf16(a, b, c, 0, 0, 0)

__device__ __forceinline__ short f2bf(float f) {
  __hip_bfloat16 h = __float2bfloat16(f);
  short s;
  __builtin_memcpy(&s, &h, 2);
  return s;
}
__device__ __forceinline__ float bf2f(short b) {
  unsigned u = ((unsigned)(unsigned short)b) << 16;
  float f;
  __builtin_memcpy(&f, &u, 4);
  return f;
}
__device__ __forceinline__ void gl_lds16(const void* g, void* l) {
  __builtin_amdgcn_global_load_lds(
      (const __attribute__((address_space(1))) void*)g,
      (__attribute__((address_space(3))) void*)l, 16, 0, 0);
}

// ---------------------------------------------------------------------------
// K1: cast fp32 -> bf16 for x, w_qkv, w_out, w_f (one thread = 4 elements)
// ---------------------------------------------------------------------------
__global__ __launch_bounds__(256) void cast_all(
    const float* __restrict__ x, const float* __restrict__ wqkv,
    const float* __restrict__ wout, const float* __restrict__ wf,
    short* __restrict__ xb, short* __restrict__ wqb,
    short* __restrict__ wob, short* __restrict__ wfb) {
  const long n_x = (long)M_ROWS * E_DIM;          // 33554432
  const long n_wq = 3L * E_DIM * E_DIM;           // 3145728
  const long n_wo = (long)E_DIM * E_DIM;          // 1048576
  long idx = ((long)blockIdx.x * 256 + threadIdx.x) * 4;
  const float* src;
  short* dst;
  if (idx < n_x) {
    src = x + idx; dst = xb + idx;
  } else if ((idx -= n_x) < n_wq) {
    src = wqkv + idx; dst = wqb + idx;
  } else if ((idx -= n_wq) < n_wo) {
    src = wout + idx; dst = wob + idx;
  } else {
    idx -= n_wo;  // w_f: 4096 elements
    src = wf + idx; dst = wfb + idx;
  }
  float4 v = *(const float4*)src;
  short4 o;
  o.x = f2bf(v.x); o.y = f2bf(v.y); o.z = f2bf(v.z); o.w = f2bf(v.w);
  *(short4*)dst = o;
}

// ---------------------------------------------------------------------------
// K2/K6 (m201-shape, R9 remap): 256x256 tile, 8 waves (2x4, each 128x64),
// BK=64, double-buffered LDS. 4 phases per K-tile, counted vmcnt(4) at tile
// boundary (never 0 in main loop), B-frags register-held, setprio on MFMA.
//
// R9 block remap (traffic fix): R9 profile showed FETCH 405 MB vs ~70 ideal
// (column-major sweep re-reads A 12x; L3 evicted by C-write stream).
// Row-band scheduling: band = blockIdx%8 (one 16-row A-band per XCD),
// i = blockIdx/8 sweeps the band's columns (16 rows x n_cols). Each A
// row-block is owned by ONE XCD (A fetched ~once, band set 8 MB in L2/L3);
// each B panel is reused 16x from L2 within a band sweep. Requires
// nwg%8==0 and (nwg/8)%16==0: K2 1536 (192=16x12) ok, K6 512 (64=16x4) ok.
// Bijective: (band, i&15) -> row 0..127, i>>4 -> col.
//
// Bank swizzle (both-sides, rule #21): slot' = slot ^ (row&7); staging source
// pre-swizzled (scb), LDS linear (m104); read slot = (kk*4+q) ^ (c&7). R9 HW:
// SQ_LDS_BANK_CONFLICT = 0. Ledger: prologue 12 loads, vmcnt(4) -> tile-0
// ready, B(1) outstanding; per tile stage A0,A1(T+1),B0,B1(T+2); boundary
// vmcnt(4) retires tile T+1 exactly. WAR/tails desk-verified (see R5-R8).
// ---------------------------------------------------------------------------
__device__ __forceinline__ void mma16q(f32x4 acc[8][4], const bf16x8 afr[2][2],
                                       const bf16x8 bfr[4][2], int m0) {
#pragma unroll
  for (int kk = 0; kk < 2; kk++)
#pragma unroll
    for (int ii = 0; ii < 2; ii++)
#pragma unroll
      for (int ni = 0; ni < 4; ni++)
        acc[m0 + ii][ni] = MFMA16(afr[ii][kk], bfr[ni][kk], acc[m0 + ii][ni]);
}

template <int OUT_F32>
__global__ __launch_bounds__(512, 2) void gemm256(
    const short* __restrict__ A, const short* __restrict__ Bm,
    void* __restrict__ Cout, const float* __restrict__ bias, int N, int K) {
  __shared__ short L[65536];  // 128 KiB
  char* Lb = (char*)L;
  const int t = threadIdx.x;
  const int w = t >> 6, l = t & 63;
  const int q = l >> 4, c = l & 15;
  const int wm = w >> 2, wn = w & 3;  // 2 x 4 wave grid

  // R9 row-band remap (see header comment)
  const int band = (int)blockIdx.x & 7;
  const int i = (int)blockIdx.x >> 3;
  const int bm = ((band << 4) + (i & 15)) << 8;  // row-block 0..127
  const int bn = (i >> 4) << 8;                  // col-block

  // Staging: half-tile = 128 rows x 128 B. Thread t: row t>>3 (+64/half),
  // src slot pre-swizzled; LDS dest linear (wave-uniform base + lane*16).
  const long Kb = (long)K * 2;
  const int srow = t >> 3;  // 0..63
  const int scb = (((t & 7) ^ ((t >> 3) & 7)) << 4);
  const char* gA = (const char*)A + (long)(bm + srow) * Kb + scb;
  const char* gB = (const char*)Bm + (long)(bn + srow) * Kb + scb;
  const long r64 = 64 * Kb;  // 64 rows in bytes

#define STAGE_A(h, srcT, dbuf)                                      \
  do {                                                              \
    const char* s_ = gA + (long)(srcT) * 128 + (long)(h) * 2 * r64; \
    char* d_ = Lb + (dbuf) * 32768 + (h) * 16384 + (w << 10);       \
    gl_lds16(s_, d_);                                               \
    gl_lds16(s_ + r64, d_ + 8192);                                  \
  } while (0)
#define STAGE_B(h, srcT, dbuf)                                      \
  do {                                                              \
    const char* s_ = gB + (long)(srcT) * 128 + (long)(h) * 2 * r64; \
    char* d_ = Lb + 65536 + (dbuf) * 32768 + (h) * 16384 + (w << 10); \
    gl_lds16(s_, d_);                                               \
    gl_lds16(s_ + r64, d_ + 8192);                                  \
  } while (0)

  // Fragment read offsets (shorts). Row stride 64 shorts; slot = 8 shorts.
  const int sw = c & 7;
  const int s0 = (q ^ sw) << 3;       // kk=0: slot (q)^(row&7), *8 shorts
  const int s1 = s0 ^ 32;             // kk=1: slot (4+q)^(row&7)
  const int aoff = wm * 8192 + c * 64;
  const int boff = 32768 + (wn >> 1) * 8192 + ((wn & 1) * 64 + c) * 64;

#define LDA(dst, mi, kk) \
  dst = *(const bf16x8*)(L + bufo + aoff + (mi) * 1024 + ((kk) ? s1 : s0))
#define LDB(dst, ni, kk) \
  dst = *(const bf16x8*)(L + bufo + boff + (ni) * 1024 + ((kk) ? s1 : s0))

  f32x4 acc[8][4];
#pragma unroll
  for (int ii = 0; ii < 8; ii++)
#pragma unroll
    for (int j = 0; j < 4; j++) acc[ii][j] = (f32x4){0.f, 0.f, 0.f, 0.f};

  const int NT = K >> 6;  // K-tiles of 64 (K=1024 -> 16)

  // Prologue: tile-0 A+B halves, then tile-1 B halves (12 loads).
  STAGE_A(0, 0, 0);
  STAGE_A(1, 0, 0);
  STAGE_B(0, 0, 0);
  STAGE_B(1, 0, 0);
  STAGE_B(0, 1, 1);
  STAGE_B(1, 1, 1);
  asm volatile("s_waitcnt vmcnt(4)\n\ts_barrier" ::: "memory");

  for (int T = 0; T < NT; ++T) {
    const int bufo = (T & 1) * 16384;            // shorts
    const int TA = (T + 1 < NT) ? T + 1 : NT - 1;  // src clamp (tail dup)
    const int TB = (T + 2 < NT) ? T + 2 : NT - 1;
    const int bufA = (T + 1) & 1;                // TRUE-target dest parity
    const int bufB = T & 1;                      // (T+2)&1 == T&1

    bf16x8 bfr[4][2], afr[2][2];

    // ---- phase 0: B all (8) + A mi0,1 (4) ; stage A0(T+1) ; MFMA mi0,1
#pragma unroll
    for (int ni = 0; ni < 4; ni++) {
      LDB(bfr[ni][0], ni, 0);
      LDB(bfr[ni][1], ni, 1);
    }
    LDA(afr[0][0], 0, 0); LDA(afr[0][1], 0, 1);
    LDA(afr[1][0], 1, 0); LDA(afr[1][1], 1, 1);
    STAGE_A(0, TA, bufA);
    __builtin_amdgcn_s_barrier();
    __builtin_amdgcn_s_setprio(1);
    mma16q(acc, afr, bfr, 0);
    __builtin_amdgcn_s_setprio(0);
    __builtin_amdgcn_s_barrier();

    // ---- phase 1: A mi2,3 ; stage A1(T+1) ; MFMA mi2,3
    LDA(afr[0][0], 2, 0); LDA(afr[0][1], 2, 1);
    LDA(afr[1][0], 3, 0); LDA(afr[1][1], 3, 1);
    STAGE_A(1, TA, bufA);
    __builtin_amdgcn_s_barrier();
    __builtin_amdgcn_s_setprio(1);
    mma16q(acc, afr, bfr, 2);
    __builtin_amdgcn_s_setprio(0);
    __builtin_amdgcn_s_barrier();

    // ---- phase 2: A mi4,5 ; stage B0(T+2) ; MFMA mi4,5
    LDA(afr[0][0], 4, 0); LDA(afr[0][1], 4, 1);
    LDA(afr[1][0], 5, 0); LDA(afr[1][1], 5, 1);
    STAGE_B(0, TB, bufB);
    __builtin_amdgcn_s_barrier();
    __builtin_amdgcn_s_setprio(1);
    mma16q(acc, afr, bfr, 4);
    __builtin_amdgcn_s_setprio(0);
    __builtin_amdgcn_s_barrier();

    // ---- phase 3: A mi6,7 ; stage B1(T+2) ; MFMA mi6,7 ; boundary vmcnt
    LDA(afr[0][0], 6, 0); LDA(afr[0][1], 6, 1);
    LDA(afr[1][0], 7, 0); LDA(afr[1][1], 7, 1);
    STAGE_B(1, TB, bufB);
    __builtin_amdgcn_s_barrier();
    __builtin_amdgcn_s_setprio(1);
    mma16q(acc, afr, bfr, 6);
    __builtin_amdgcn_s_setprio(0);
    // counted boundary wait: tile T+1's 4 halves retired; B(T+2) in flight
    asm volatile("s_waitcnt vmcnt(4)\n\ts_barrier" ::: "memory");
  }
  // drain outstanding gl_lds before LDS dealloc / kernel exit
  asm volatile("s_waitcnt vmcnt(0)" ::: "memory");

#undef STAGE_A
#undef STAGE_B
#undef LDA
#undef LDB

  // Epilogue: C/D layout col = c, row = q*4 + r (m89-verified)
  if (OUT_F32) {
    float* C = (float*)Cout;
#pragma unroll
    for (int ni = 0; ni < 4; ni++) {
      int n = bn + (wn << 6) + ni * 16 + c;
      float bo = bias[n];
#pragma unroll
      for (int mi = 0; mi < 8; mi++)
#pragma unroll
        for (int r = 0; r < 4; r++) {
          int m = bm + (wm << 7) + mi * 16 + (q << 2) + r;
          C[(long)m * N + n] = acc[mi][ni][r] + bo;
        }
    }
  } else {
    short* C = (short*)Cout;
#pragma unroll
    for (int ni = 0; ni < 4; ni++) {
      int n = bn + (wn << 6) + ni * 16 + c;
#pragma unroll
      for (int mi = 0; mi < 8; mi++)
#pragma unroll
        for (int r = 0; r < 4; r++) {
          int m = bm + (wm << 7) + mi * 16 + (q << 2) + r;
          C[(long)m * N + n] = f2bf(acc[mi][ni][r]);
        }
    }
  }
}

// ---------------------------------------------------------------------------
// K3: feature map. Per block: (h, b, 256 s rows); wave handles 64 s.
//   Qp[h,b,s,p]  = relu(q . w_f[p] + b_f[p])           (A=q rows, B=w_f rows)
//   KpT[h,b,p,s] = relu(k . w_f[p] + b_f[p])           (A=w_f rows, B=k rows)
//   VT[h,b,d,s]  = v[s,d]                              (A=identity, B=v rows)
// ---------------------------------------------------------------------------
__global__ __launch_bounds__(256) void feature_kernel(
    const short* __restrict__ qkv, const short* __restrict__ wfb,
    const float* __restrict__ b_f, short* __restrict__ Qp,
    short* __restrict__ KpT, short* __restrict__ VT) {
  const int bx = blockIdx.x;
  const int sblk = bx & 15, b = (bx >> 4) & 7, h = bx >> 7;
  const int t = threadIdx.x, w = t >> 6, l = t & 63;
  const int q = l >> 4, c = l & 15;
  const int s_base = sblk * 256 + w * 64;
  const int hb = h * 8 + b;

  bf16x8 wf[4][2];
#pragma unroll
  for (int ti = 0; ti < 4; ti++)
#pragma unroll
    for (int kk = 0; kk < 2; kk++)
      wf[ti][kk] = *(const bf16x8*)(wfb + (ti * 16 + c) * 64 + kk * 32 + q * 8);

  float bfc[4];
#pragma unroll
  for (int ni = 0; ni < 4; ni++) bfc[ni] = b_f[ni * 16 + c];

  f32x4 acc[4][4];
  bf16x8 xf[4][2];

  // ---- Phase Q: Qp (s-major) ----
#pragma unroll
  for (int i = 0; i < 4; i++)
#pragma unroll
    for (int j = 0; j < 4; j++) acc[i][j] = (f32x4){0.f, 0.f, 0.f, 0.f};
#pragma unroll
  for (int mi = 0; mi < 4; mi++) {
    long ridx = (long)((s_base + mi * 16 + c) * 8 + b) * N_QKV;
#pragma unroll
    for (int kk = 0; kk < 2; kk++)
      xf[mi][kk] = *(const bf16x8*)(qkv + ridx + h * 64 + kk * 32 + q * 8);
  }
#pragma unroll
  for (int kk = 0; kk < 2; kk++)
#pragma unroll
    for (int mi = 0; mi < 4; mi++)
#pragma unroll
      for (int ni = 0; ni < 4; ni++)
        acc[mi][ni] = MFMA16(xf[mi][kk], wf[ni][kk], acc[mi][ni]);
#pragma unroll
  for (int mi = 0; mi < 4; mi++)
#pragma unroll
    for (int ni = 0; ni < 4; ni++)
#pragma unroll
      for (int r = 0; r < 4; r++) {
        int s = s_base + mi * 16 + q * 4 + r;
        float v = acc[mi][ni][r] + bfc[ni];
        v = fmaxf(v, 0.f);
        Qp[((long)hb * S_LEN + s) * 64 + ni * 16 + c] = f2bf(v);
      }

  // ---- Phase K: KpT (p-major) via operand swap ----
#pragma unroll
  for (int i = 0; i < 4; i++)
#pragma unroll
    for (int j = 0; j < 4; j++) acc[i][j] = (f32x4){0.f, 0.f, 0.f, 0.f};
#pragma unroll
  for (int si = 0; si < 4; si++) {
    long ridx = (long)((s_base + si * 16 + c) * 8 + b) * N_QKV;
#pragma unroll
    for (int kk = 0; kk < 2; kk++)
      xf[si][kk] =
          *(const bf16x8*)(qkv + ridx + E_DIM + h * 64 + kk * 32 + q * 8);
  }
#pragma unroll
  for (int kk = 0; kk < 2; kk++)
#pragma unroll
    for (int pi = 0; pi < 4; pi++)
#pragma unroll
      for (int si = 0; si < 4; si++)
        acc[pi][si] = MFMA16(wf[pi][kk], xf[si][kk], acc[pi][si]);
#pragma unroll
  for (int pi = 0; pi < 4; pi++)
#pragma unroll
    for (int r = 0; r < 4; r++) {
      int p = pi * 16 + q * 4 + r;
      float bb = b_f[p];
#pragma unroll
      for (int si = 0; si < 4; si++) {
        int s = s_base + si * 16 + c;
        float v = acc[pi][si][r] + bb;
        v = fmaxf(v, 0.f);
        KpT[((long)hb * 64 + p) * S_LEN + s] = f2bf(v);
      }
    }

  // ---- Phase V: VT (d-major) via identity-A MFMA (exact passthrough) ----
  bf16x8 id0 = {0, 0, 0, 0, 0, 0, 0, 0}, id1 = {0, 0, 0, 0, 0, 0, 0, 0};
#pragma unroll
  for (int j = 0; j < 8; j++) {
    int k = q * 8 + j;
    id0[j] = (short)((k == c) ? 0x3F80 : 0);
    id1[j] = (short)((k == c + 16) ? 0x3F80 : 0);
  }
#pragma unroll
  for (int i = 0; i < 4; i++)
#pragma unroll
    for (int j = 0; j < 4; j++) acc[i][j] = (f32x4){0.f, 0.f, 0.f, 0.f};
#pragma unroll
  for (int si = 0; si < 4; si++) {
    long ridx = (long)((s_base + si * 16 + c) * 8 + b) * N_QKV;
#pragma unroll
    for (int kc = 0; kc < 2; kc++)
      xf[si][kc] =
          *(const bf16x8*)(qkv + ridx + 2 * E_DIM + h * 64 + kc * 32 + q * 8);
  }
#pragma unroll
  for (int kc = 0; kc < 2; kc++)
#pragma unroll
    for (int si = 0; si < 4; si++) {
      acc[kc * 2 + 0][si] = MFMA16(id0, xf[si][kc], acc[kc * 2 + 0][si]);
      acc[kc * 2 + 1][si] = MFMA16(id1, xf[si][kc], acc[kc * 2 + 1][si]);
    }
#pragma unroll
  for (int dt = 0; dt < 4; dt++)
#pragma unroll
    for (int si = 0; si < 4; si++)
#pragma unroll
      for (int r = 0; r < 4; r++) {
        int d = (dt >> 1) * 32 + (dt & 1) * 16 + q * 4 + r;
        int s = s_base + si * 16 + c;
        VT[((long)hb * 64 + d) * S_LEN + s] = f2bf(acc[dt][si][r]);
      }
}

// ---------------------------------------------------------------------------
// K4 (R9: +ksum fold): kv (stored transposed: kvT[d][p] = sum_s v[s,d]*k_p),
// fp32 atomics. ksum[p] = sum_s KpT[p][s] computed via an all-ones A-fragment
// MFMA against the same bfr (KpT) operand: every output row of ones*KpT^T is
// exactly sum_s KpT[p][s] (fp32 accumulate, same as the old ksum_kernel
// modulo summation order). One atomicAdd per (wave, p) with q==0 lanes.
// Eliminates ksum_kernel's full 64 MB re-read of KpT.
// ---------------------------------------------------------------------------
__global__ __launch_bounds__(256) void kv_kernel(const short* __restrict__ KpT,
                                                 const short* __restrict__ VT,
                                                 float* __restrict__ kvf,
                                                 float* __restrict__ ksumf) {
  const int hb = blockIdx.y, sc = blockIdx.x;
  const int t = threadIdx.x, w = t >> 6, l = t & 63;
  const int q = l >> 4, c = l & 15;
  const int s0 = sc * 512 + w * 128;
  const short* vb = VT + (long)hb * 64 * S_LEN;
  const short* kb = KpT + (long)hb * 64 * S_LEN;

  bf16x8 ones;
#pragma unroll
  for (int j = 0; j < 8; j++) ones[j] = (short)0x3F80;

  f32x4 acc[4][4], acc5[4];
#pragma unroll
  for (int i = 0; i < 4; i++) {
    acc5[i] = (f32x4){0.f, 0.f, 0.f, 0.f};
#pragma unroll
    for (int j = 0; j < 4; j++) acc[i][j] = (f32x4){0.f, 0.f, 0.f, 0.f};
  }

  for (int it = 0; it < 4; it++) {
    int so = s0 + it * 32 + q * 8;
    bf16x8 af[4], bfr[4];
#pragma unroll
    for (int di = 0; di < 4; di++)
      af[di] = *(const bf16x8*)(vb + (long)(di * 16 + c) * S_LEN + so);
#pragma unroll
    for (int pi = 0; pi < 4; pi++)
      bfr[pi] = *(const bf16x8*)(kb + (long)(pi * 16 + c) * S_LEN + so);
#pragma unroll
    for (int di = 0; di < 4; di++)
#pragma unroll
      for (int pi = 0; pi < 4; pi++)
        acc[di][pi] = MFMA16(af[di], bfr[pi], acc[di][pi]);
#pragma unroll
    for (int pi = 0; pi < 4; pi++)
      acc5[pi] = MFMA16(ones, bfr[pi], acc5[pi]);
  }

  __shared__ float red[4][4096];
#pragma unroll
  for (int di = 0; di < 4; di++)
#pragma unroll
    for (int pi = 0; pi < 4; pi++)
#pragma unroll
      for (int r = 0; r < 4; r++)
        red[w][(di * 16 + q * 4 + r) * 64 + pi * 16 + c] = acc[di][pi][r];
  __syncthreads();
  float* dst = kvf + (long)hb * 4096;
  for (int i = 0; i < 16; i++) {
    int idx = i * 256 + t;
    float s = red[0][idx] + red[1][idx] + red[2][idx] + red[3][idx];
    atomicAdd(dst + idx, s);
  }
  // ksum partials: rows of acc5 are identical; use q==0 lanes, reg 0.
  if (q == 0) {
#pragma unroll
    for (int pi = 0; pi < 4; pi++)
      atomicAdd(ksumf + hb * 64 + pi * 16 + c, acc5[pi][0]);
  }
}

// R9: also casts ksumf (8192 f32) -> ksum bf16. Grid 2080 x 256.
__global__ __launch_bounds__(256) void kv_cast(const float* __restrict__ kvf,
                                               short* __restrict__ kvb,
                                               const float* __restrict__ ksumf,
                                               short* __restrict__ ksum) {
  int i = blockIdx.x * 256 + threadIdx.x;
  if (i < 524288) {
    kvb[i] = f2bf(kvf[i]);
  } else if (i < 524288 + 8192) {
    int j = i - 524288;
    ksum[j] = f2bf(ksumf[j]);
  }
}

// ---------------------------------------------------------------------------
// K5: num = Qp @ kvT^T (K=64), norm via masked-b_frag MFMA column, divide,
// write attn into (S,B,E) bf16 layout.
// ---------------------------------------------------------------------------
__global__ __launch_bounds__(256) void attn_kernel(
    const short* __restrict__ Qp, const short* __restrict__ kvb,
    const short* __restrict__ ksum, short* __restrict__ attn) {
  const int bx = blockIdx.x;
  const int sblk = bx & 15, b = (bx >> 4) & 7, h = bx >> 7;
  const int t = threadIdx.x, w = t >> 6, l = t & 63;
  const int q = l >> 4, c = l & 15;
  const int s_base = sblk * 256 + w * 64;
  const int hb = h * 8 + b;

  bf16x8 bkv[4][2];
#pragma unroll
  for (int ni = 0; ni < 4; ni++)
#pragma unroll
    for (int kk = 0; kk < 2; kk++)
      bkv[ni][kk] = *(const bf16x8*)(kvb + (long)hb * 4096 +
                                     (ni * 16 + c) * 64 + kk * 32 + q * 8);
  bf16x8 bn[2];
  const bf16x8 zfrag = {0, 0, 0, 0, 0, 0, 0, 0};
#pragma unroll
  for (int kk = 0; kk < 2; kk++) {
    bf16x8 v = *(const bf16x8*)(ksum + hb * 64 + kk * 32 + q * 8);
    bn[kk] = (c == 0) ? v : zfrag;
  }

  bf16x8 af[4][2];
#pragma unroll
  for (int mi = 0; mi < 4; mi++)
#pragma unroll
    for (int kk = 0; kk < 2; kk++)
      af[mi][kk] = *(const bf16x8*)(Qp + ((long)hb * S_LEN + s_base + mi * 16 + c) * 64 +
                                    kk * 32 + q * 8);

  f32x4 acc[4][4], accn[4];
#pragma unroll
  for (int i = 0; i < 4; i++) {
    accn[i] = (f32x4){0.f, 0.f, 0.f, 0.f};
#pragma unroll
    for (int j = 0; j < 4; j++) acc[i][j] = (f32x4){0.f, 0.f, 0.f, 0.f};
  }
#pragma unroll
  for (int kk = 0; kk < 2; kk++)
#pragma unroll
    for (int mi = 0; mi < 4; mi++) {
      accn[mi] = MFMA16(af[mi][kk], bn[kk], accn[mi]);
#pragma unroll
      for (int ni = 0; ni < 4; ni++)
        acc[mi][ni] = MFMA16(af[mi][kk], bkv[ni][kk], acc[mi][ni]);
    }

#pragma unroll
  for (int mi = 0; mi < 4; mi++)
#pragma unroll
    for (int r = 0; r < 4; r++) {
      float nv = __shfl(accn[mi][r], l & 48, 64);  // col-0 lane of this quad
      float inv = 1.f / (nv + 1e-8f);
      int s = s_base + mi * 16 + q * 4 + r;
#pragma unroll
      for (int ni = 0; ni < 4; ni++) {
        float v = acc[mi][ni][r] * inv;
        attn[((long)s * 8 + b) * E_DIM + h * 64 + ni * 16 + c] = f2bf(v);
      }
    }
}

// ---------------------------------------------------------------------------
// Launch
// ---------------------------------------------------------------------------
extern "C" void kernel_launch(void* const* d_in, const int* in_sizes, int n_in,
                              void* d_out, int out_size, void* d_ws,
                              size_t ws_size, hipStream_t stream) {
  const float* x = (const float*)d_in[0];
  const float* w_qkv = (const float*)d_in[1];
  const float* w_out = (const float*)d_in[2];
  const float* b_out = (const float*)d_in[3];
  const float* w_f = (const float*)d_in[4];
  const float* b_f = (const float*)d_in[5];

  char* ws = (char*)d_ws;
  // workspace layout (bytes); total ~459 MiB (unchanged footprint)
  constexpr size_t off_xb = 0;                       // 64 MB (aliased by attn)
  constexpr size_t off_wqb = 67108864;               // 6 MB
  constexpr size_t off_wob = off_wqb + 6291456;      // 2 MB
  constexpr size_t off_wfb = off_wob + 2097152;      // 8 KB
  constexpr size_t off_qkv = off_wfb + 8192;         // 192 MB (dead after K3)
  constexpr size_t off_Qp = off_qkv + 201326592;     // 64 MB
  constexpr size_t off_KpT = off_Qp + 67108864;      // 64 MB
  constexpr size_t off_VT = off_KpT + 67108864;      // 64 MB
  constexpr size_t off_kvf = off_VT + 67108864;      // 2 MB
  constexpr size_t off_kvb = off_kvf + 2097152;      // 1 MB
  constexpr size_t off_ksum = off_kvb + 1048576;     // 16 KB

  short* xb = (short*)(ws + off_xb);
  short* wqb = (short*)(ws + off_wqb);
  short* wob = (short*)(ws + off_wob);
  short* wfb = (short*)(ws + off_wfb);
  short* qkv = (short*)(ws + off_qkv);
  short* Qp = (short*)(ws + off_Qp);
  short* KpT = (short*)(ws + off_KpT);
  short* VT = (short*)(ws + off_VT);
  float* kvf = (float*)(ws + off_kvf);
  short* kvb = (short*)(ws + off_kvb);
  short* ksum = (short*)(ws + off_ksum);
  float* ksumf = (float*)(ws + off_qkv);  // 32 KB in dead qkv region
  short* attn = xb;  // alias: xb dead after QKV GEMM

  // K1: casts (37752832 elements / 4 per thread)
  cast_all<<<36868, 256, 0, stream>>>(x, w_qkv, w_out, w_f, xb, wqb, wob, wfb);

  // K2: qkv = xb @ wqb^T  (M=32768, N=3072, K=1024); 1536 blocks (8 bands)
  gemm256<0><<<1536, 512, 0, stream>>>(xb, wqb, qkv, nullptr, N_QKV, E_DIM);

  // K3: feature maps + transposes
  feature_kernel<<<2048, 256, 0, stream>>>(qkv, wfb, b_f, Qp, KpT, VT);

  // K4: kv accumulation + ksum fold (zero-init both; ws poisoned each call)
  hipMemsetAsync(kvf, 0, (size_t)HB_DIM * 4096 * 4, stream);
  hipMemsetAsync(ksumf, 0, (size_t)HB_DIM * 64 * 4, stream);
  kv_kernel<<<dim3(8, HB_DIM), 256, 0, stream>>>(KpT, VT, kvf, ksumf);
  kv_cast<<<2080, 256, 0, stream>>>(kvf, kvb, ksumf, ksum);

  // K5: attn = (Qp @ kv) / (Qp . ksum), into (S,B,E) bf16
  attn_kernel<<<2048, 256, 0, stream>>>(Qp, kvb, ksum, attn);

  // K6: out = attn @ w_out^T + b_out  (fp32); 512 blocks (8 bands)
  gemm256<1><<<512, 512, 0, stream>>>(attn, wob, (float*)d_out, b_out,
                                      E_DIM, E_DIM);
}